// Round 3
// baseline (6665.517 us; speedup 1.0000x reference)
//
#include <hip/hip_runtime.h>
#include <hip/hip_bf16.h>

typedef __bf16 bf16;
typedef bf16 bf16x8 __attribute__((ext_vector_type(8)));
typedef float f32x4 __attribute__((ext_vector_type(4)));
typedef unsigned int u32;
typedef u32 u32x4 __attribute__((ext_vector_type(4)));

#define AGENT __HIP_MEMORY_SCOPE_AGENT

// ---- problem sizes ----
#define TT 512
#define BB 64
#define HH 512
#define TB (TT*BB)      // 32768 rows
#define G3 (3*HH)       // 1536 gates per dir

// ---- workspace layout (bytes) ----
#define GI_OFF   0L
#define GI_BYTES (2L*TB*G3*2)          // bf16 gi, both dirs
#define L0_OFF   (GI_OFF + GI_BYTES)
#define L0_BYTES (1L*TB*1024*2)        // bf16 layer-0 output
#define XB_OFF   (L0_OFF + L0_BYTES)
#define XB_BYTES (1L*TB*512*2)         // bf16 x
#define W0_OFF   (XB_OFF + XB_BYTES)
#define W0_BYTES (3072L*512*2)         // packed w_ih L0 (f then b)
#define W1_OFF   (W0_OFF + W0_BYTES)
#define W1_BYTES (3072L*1024*2)        // packed w_ih L1
#define HB_OFF   (W1_OFF + W1_BYTES)
#define HB_BYTES (2L*2*64*256*4)       // h exchange: [phase][dir][64][256] u32 (bf16 pairs)
#define FL_OFF   (HB_OFF + HB_BYTES)
#define FL_BYTES 1024                  // (unused; kept for ws sizing stability)
#define WS_NEED  (FL_OFF + FL_BYTES)

// ============================ helpers ============================
__device__ __forceinline__ float sigm(float x) {
    return __builtin_amdgcn_rcpf(1.0f + __expf(-x));
}
__device__ __forceinline__ float tanh_f(float x) {
    return 1.0f - 2.0f * __builtin_amdgcn_rcpf(1.0f + __expf(2.0f * x));
}

// ============================ kernels ============================
__global__ void sentinel(float* o) { o[0] = 1.0e9f; }  // ws too small marker

__global__ void cvt_f32_bf16(const float* __restrict__ s, bf16* __restrict__ d, long n) {
    long i = (long)blockIdx.x * blockDim.x + threadIdx.x;
    long st = (long)gridDim.x * blockDim.x;
    for (; i < n; i += st) d[i] = (bf16)s[i];
}

// C[m, n] = sum_k A[m,k] * Bw[n,k]; A row-major [32768,K] bf16, Bw [3072,K] bf16.
// Output written as bf16 into gi[dir][m][col], dir = n>=1536.
__global__ __launch_bounds__(256, 2)
void gemm_gi(const bf16* __restrict__ A, const bf16* __restrict__ Bw,
             bf16* __restrict__ gi, int K)
{
    __shared__ bf16 aS[128*72];
    __shared__ bf16 bS[128*72];
    const int tid = threadIdx.x;
    const int mt = blockIdx.x & 255;
    const int nt = blockIdx.x >> 8;
    const long m0 = (long)mt * 128;
    const int n0 = nt * 128;
    const int wave = tid >> 6, lane = tid & 63;
    const int q = lane >> 4, lr = lane & 15;
    const int wm = wave & 1, wn = wave >> 1;
    f32x4 acc[4][4] = {};

    for (int kb = 0; kb < K; kb += 64) {
        __syncthreads();
        #pragma unroll
        for (int p = 0; p < 4; ++p) {
            int idx = tid + p * 256;
            int row = idx >> 3, qd = idx & 7;
            *(uint4*)(aS + row*72 + qd*8) = *(const uint4*)(A + (m0+row)*K + kb + qd*8);
            *(uint4*)(bS + row*72 + qd*8) = *(const uint4*)(Bw + (long)(n0+row)*K + kb + qd*8);
        }
        __syncthreads();
        #pragma unroll
        for (int kk = 0; kk < 2; ++kk) {
            bf16x8 af[4], bfr[4];
            #pragma unroll
            for (int sm = 0; sm < 4; ++sm)
                af[sm] = *(const bf16x8*)(aS + (wm*64 + sm*16 + lr)*72 + kk*32 + q*8);
            #pragma unroll
            for (int sn = 0; sn < 4; ++sn)
                bfr[sn] = *(const bf16x8*)(bS + (wn*64 + sn*16 + lr)*72 + kk*32 + q*8);
            #pragma unroll
            for (int sm = 0; sm < 4; ++sm)
                #pragma unroll
                for (int sn = 0; sn < 4; ++sn)
                    acc[sm][sn] = __builtin_amdgcn_mfma_f32_16x16x32_bf16(
                        af[sm], bfr[sn], acc[sm][sn], 0, 0, 0);
        }
    }
    #pragma unroll
    for (int sm = 0; sm < 4; ++sm) {
        #pragma unroll
        for (int sn = 0; sn < 4; ++sn) {
            int n_g = n0 + wn*64 + sn*16 + lr;
            int d = (n_g >= G3) ? 1 : 0;
            int cg = n_g - d * G3;
            u32* gout = (u32*)(gi + (long)d * TB * G3);
            #pragma unroll
            for (int i = 0; i < 4; ++i) {
                long m_g = m0 + wm*64 + sm*16 + q*4 + i;
                unsigned short hs = __builtin_bit_cast(unsigned short, (bf16)acc[sm][sn][i]);
                int other = __shfl_xor((int)hs, 1, 64);
                if (!(lr & 1))
                    gout[(m_g * G3 + cg) >> 1] = (u32)hs | (((u32)(unsigned short)other) << 16);
            }
        }
    }
}

// Persistent recurrence: 32 blocks (2 dirs x 16 h-slices of 32 cols), 256 thr.
//
// Round-3 change: 32-col slices (was 16). Halves the all-to-all fabric
// traffic (each block still ingests the full 64KB h per step, but there are
// half as many blocks: 2MB/step total vs 4MB) and halves the producer
// fan-in (16 blocks per barrier group instead of 32 -> smaller straggler
// max). Per-wave compute doubles (96 MFMAs, 6 accumulators) - still far
// below step latency. W_hh slice in LDS doubles to 96KB (fits 160KB/CU).
//
// Sync protocol (unchanged from round 2): SELF-VALIDATING DATA.
// GRU guarantees |h| < 1 < 2, so bit14 of every published bf16 (exponent
// MSB) is always 0. tag(d) = (d>>1)&1 for generation d in phase buffer d&1.
// Producer ORs the tag into each packed u32 and stores fire-and-forget
// (relaxed agent scope). Consumer polls by loading the h tile itself with
// sc0 sc1 and validating every u32's tag; torn old/new mixes are caught
// per-u32. Tag bits are STRIPPED (AND 0xBFFFBFFF) before the MFMAs (bit14
// = x2^128). Deadlock-free by induction from the pre-loop publish(0);
// ABA-free because gen d+2 cannot exist before all blocks consumed gen d+1.
__global__ __launch_bounds__(256, 1)
void gru_rec(const bf16* __restrict__ gi,
             const float* __restrict__ whh_f, const float* __restrict__ whh_b,
             const float* __restrict__ bih_f, const float* __restrict__ bhh_f,
             const float* __restrict__ bih_b, const float* __restrict__ bhh_b,
             const float* __restrict__ h0,
             u32* hbuf,
             void* out, float* hn_out, int layer, int out_f32)
{
    __shared__ bf16 wS[96*512];   // 96KB; XOR-swizzled: chunk c stored at c^(row&7)
    const int tid = threadIdx.x;
    const int dir = blockIdx.x & 1;
    const int cs  = blockIdx.x >> 1;         // 0..15, 32-col slice
    const int wave = tid >> 6, lane = tid & 63;
    const int q = lane >> 4, lr = lane & 15;

    const float* whh = dir ? whh_b : whh_f;
    const float* bih = dir ? bih_b : bih_f;
    const float* bhh = dir ? bhh_b : bhh_f;

    // stage W_hh slice -> LDS bf16: 96 rows (= gate g*32 + hcol hc), 512 K.
    for (int idx = tid; idx < 96*64; idx += 256) {
        int row = idx >> 6, c = idx & 63;
        int g = row >> 5, hc = row & 31;
        const float* src = whh + (size_t)(g*HH + cs*32 + hc)*HH + c*8;
        bf16x8 v;
        #pragma unroll
        for (int j = 0; j < 8; ++j) v[j] = (bf16)src[j];
        *(bf16x8*)(wS + row*512 + ((c ^ (row & 7)) << 3)) = v;
    }
    __syncthreads();

    // biases for the thread's 2 col-tiles (ct=0,1): col = cs*32 + ct*16 + lr
    float bi[3][2], bh[3][2];
    #pragma unroll
    for (int g = 0; g < 3; ++g)
        #pragma unroll
        for (int ct = 0; ct < 2; ++ct) {
            int c = g*HH + cs*32 + ct*16 + lr;
            bi[g][ct] = bih[c];
            bh[g][ct] = bhh[c];
        }
    const int mrow = wave*16 + q*4;

    float hprev[2][4];
    #pragma unroll
    for (int ct = 0; ct < 2; ++ct)
        #pragma unroll
        for (int i = 0; i < 4; ++i)
            hprev[ct][i] = h0[((2*layer + dir)*BB + mrow + i)*HH + cs*32 + ct*16 + lr];

    // publish hv[][] into phase buffer ph with tag pattern pat (fire-and-forget)
    auto publish = [&](int ph, u32 pat, const float (*hv)[4]) {
        u32* hb = hbuf + (((ph << 1) | dir) * 64) * 256;
        #pragma unroll
        for (int ct = 0; ct < 2; ++ct) {
            int cp = (cs*32 + ct*16 + lr) >> 1;      // u32 col (lr even writes)
            #pragma unroll
            for (int i = 0; i < 4; ++i) {
                unsigned short hs = __builtin_bit_cast(unsigned short, (bf16)hv[ct][i]);
                int other = __shfl_xor((int)hs, 1, 64);
                if (!(lr & 1)) {
                    u32 u = ((u32)hs | (((u32)(unsigned short)other) << 16)) | pat;
                    __hip_atomic_store(hb + (mrow + i)*256 + cp, u,
                                       __ATOMIC_RELAXED, AGENT);
                }
            }
        }
    };

    // initial h publish: generation d=0, phase 0, tag 0 (needs |h0|<2; h0=0 here)
    publish(0, 0u, hprev);

    const bf16* gbase = gi + (long)dir * TB * G3;
    bf16 gp[3][2][4];
    {
        int t0 = dir ? (TT-1) : 0;
        #pragma unroll
        for (int g = 0; g < 3; ++g)
            #pragma unroll
            for (int ct = 0; ct < 2; ++ct)
                #pragma unroll
                for (int i = 0; i < 4; ++i)
                    gp[g][ct][i] = gbase[(long)(t0*BB + mrow + i)*G3 + g*HH + cs*32 + ct*16 + lr];
    }

    const int sw = lr & 7;

    for (int s = 0; s < TT; ++s) {
        const int t = dir ? (TT-1-s) : s;
        const u32 pat = (s & 2) ? 0x40004000u : 0u;   // tag(d=s) = (s>>1)&1
        const u32* hr = hbuf + ((((s & 1) << 1) | dir)*64 + wave*16 + lr)*256 + q*4;
        u32x4 a0,a1,a2,a3,a4,a5,a6,a7,a8,a9,a10,a11,a12,a13,a14,a15;
        // ---- poll-the-data: load 16x dwordx4 (L1/L2-bypassing), validate tags
        for (;;) {
            asm volatile(
                "global_load_dwordx4 %0, %16, off sc0 sc1\n\t"
                "global_load_dwordx4 %1, %16, off offset:64 sc0 sc1\n\t"
                "global_load_dwordx4 %2, %16, off offset:128 sc0 sc1\n\t"
                "global_load_dwordx4 %3, %16, off offset:192 sc0 sc1\n\t"
                "global_load_dwordx4 %4, %16, off offset:256 sc0 sc1\n\t"
                "global_load_dwordx4 %5, %16, off offset:320 sc0 sc1\n\t"
                "global_load_dwordx4 %6, %16, off offset:384 sc0 sc1\n\t"
                "global_load_dwordx4 %7, %16, off offset:448 sc0 sc1\n\t"
                "global_load_dwordx4 %8, %16, off offset:512 sc0 sc1\n\t"
                "global_load_dwordx4 %9, %16, off offset:576 sc0 sc1\n\t"
                "global_load_dwordx4 %10, %16, off offset:640 sc0 sc1\n\t"
                "global_load_dwordx4 %11, %16, off offset:704 sc0 sc1\n\t"
                "global_load_dwordx4 %12, %16, off offset:768 sc0 sc1\n\t"
                "global_load_dwordx4 %13, %16, off offset:832 sc0 sc1\n\t"
                "global_load_dwordx4 %14, %16, off offset:896 sc0 sc1\n\t"
                "global_load_dwordx4 %15, %16, off offset:960 sc0 sc1\n\t"
                "s_waitcnt vmcnt(0)"
                : "=&v"(a0),"=&v"(a1),"=&v"(a2),"=&v"(a3),
                  "=&v"(a4),"=&v"(a5),"=&v"(a6),"=&v"(a7),
                  "=&v"(a8),"=&v"(a9),"=&v"(a10),"=&v"(a11),
                  "=&v"(a12),"=&v"(a13),"=&v"(a14),"=&v"(a15)
                : "v"(hr)
                : "memory");
#define ORV(v)  (v[0] | v[1] | v[2] | v[3])
#define ANDV(v) (v[0] & v[1] & v[2] & v[3])
            bool ok;
            if (pat) {
                u32 g = ANDV(a0) & ANDV(a1) & ANDV(a2)  & ANDV(a3)
                      & ANDV(a4) & ANDV(a5) & ANDV(a6)  & ANDV(a7)
                      & ANDV(a8) & ANDV(a9) & ANDV(a10) & ANDV(a11)
                      & ANDV(a12)& ANDV(a13)& ANDV(a14) & ANDV(a15);
                ok = (g & 0x40004000u) == 0x40004000u;
            } else {
                u32 b = ORV(a0) | ORV(a1) | ORV(a2)  | ORV(a3)
                      | ORV(a4) | ORV(a5) | ORV(a6)  | ORV(a7)
                      | ORV(a8) | ORV(a9) | ORV(a10) | ORV(a11)
                      | ORV(a12)| ORV(a13)| ORV(a14) | ORV(a15);
                ok = (b & 0x40004000u) == 0u;
            }
#undef ORV
#undef ANDV
            if (__all((int)ok)) break;
        }
        // ---- strip tag bits (bit14 == x2^128 -- must NOT reach the MFMAs)
        {
            const u32 SM = pat ? 0xBFFFBFFFu : 0xFFFFFFFFu;
            auto strip = [&](u32x4& v) {
                v[0] &= SM; v[1] &= SM; v[2] &= SM; v[3] &= SM;
            };
            strip(a0);  strip(a1);  strip(a2);  strip(a3);
            strip(a4);  strip(a5);  strip(a6);  strip(a7);
            strip(a8);  strip(a9);  strip(a10); strip(a11);
            strip(a12); strip(a13); strip(a14); strip(a15);
        }
        // ---- 96 MFMAs (gh = h @ W_slice^T, 3 gates x 2 col-tiles)
        f32x4 acc[3][2] = {};
#define KSTEP(KK, AU) { \
            bf16x8 av = __builtin_bit_cast(bf16x8, AU); \
            int c0 = (((KK)*4 + q) ^ sw) << 3; \
            _Pragma("unroll") \
            for (int g = 0; g < 3; ++g) { \
                _Pragma("unroll") \
                for (int ct = 0; ct < 2; ++ct) { \
                    bf16x8 b = *(const bf16x8*)(wS + (g*32 + ct*16 + lr)*512 + c0); \
                    acc[g][ct] = __builtin_amdgcn_mfma_f32_16x16x32_bf16(av, b, acc[g][ct], 0,0,0); \
                } \
            } }
        KSTEP(0,a0)  KSTEP(1,a1)  KSTEP(2,a2)  KSTEP(3,a3)
        KSTEP(4,a4)  KSTEP(5,a5)  KSTEP(6,a6)  KSTEP(7,a7)
        KSTEP(8,a8)  KSTEP(9,a9)  KSTEP(10,a10) KSTEP(11,a11)
        KSTEP(12,a12) KSTEP(13,a13) KSTEP(14,a14) KSTEP(15,a15)
#undef KSTEP
        // ---- fused gates (fp32)
        float hnew[2][4];
        #pragma unroll
        for (int ct = 0; ct < 2; ++ct)
            #pragma unroll
            for (int i = 0; i < 4; ++i) {
                float r = sigm((float)gp[0][ct][i] + bi[0][ct] + acc[0][ct][i] + bh[0][ct]);
                float z = sigm((float)gp[1][ct][i] + bi[1][ct] + acc[1][ct][i] + bh[1][ct]);
                float n = tanh_f((float)gp[2][ct][i] + bi[2][ct] + r * (acc[2][ct][i] + bh[2][ct]));
                float h = (1.0f - z) * n + z * hprev[ct][i];
                hprev[ct][i] = h;
                hnew[ct][i] = h;
            }
        // ---- publish h_new immediately (self-validating: no ack, no flag)
        if (s < TT-1) {
            u32 npat = ((s+1) & 2) ? 0x40004000u : 0u;  // tag(d=s+1)
            publish((s+1) & 1, npat, hnew);
        }
        // ---- write y[t]
        if (out_f32) {
            float* yo = (float*)out;
            #pragma unroll
            for (int ct = 0; ct < 2; ++ct)
                #pragma unroll
                for (int i = 0; i < 4; ++i)
                    yo[(long)(t*BB + mrow + i)*1024 + dir*HH + cs*32 + ct*16 + lr] = hnew[ct][i];
        } else {
            bf16* yo = (bf16*)out;
            #pragma unroll
            for (int ct = 0; ct < 2; ++ct)
                #pragma unroll
                for (int i = 0; i < 4; ++i)
                    yo[(long)(t*BB + mrow + i)*1024 + dir*HH + cs*32 + ct*16 + lr] = (bf16)hnew[ct][i];
        }
        if (s == TT-1) {
            #pragma unroll
            for (int ct = 0; ct < 2; ++ct)
                #pragma unroll
                for (int i = 0; i < 4; ++i)
                    hn_out[((2*layer + dir)*BB + mrow + i)*HH + cs*32 + ct*16 + lr] = hnew[ct][i];
            break;
        }
        // ---- prefetch next gi (hides under the next poll)
        int tn = dir ? (TT-2-s) : (s+1);
        #pragma unroll
        for (int g = 0; g < 3; ++g)
            #pragma unroll
            for (int ct = 0; ct < 2; ++ct)
                #pragma unroll
                for (int i = 0; i < 4; ++i)
                    gp[g][ct][i] = gbase[(long)(tn*BB + mrow + i)*G3 + g*HH + cs*32 + ct*16 + lr];
    }
}

// ============================ launch ============================
extern "C" void kernel_launch(void* const* d_in, const int* in_sizes, int n_in,
                              void* d_out, int out_size, void* d_ws, size_t ws_size,
                              hipStream_t stream)
{
    const float* x     = (const float*)d_in[0];
    const float* h0    = (const float*)d_in[1];
    const float* wih0f = (const float*)d_in[2];
    const float* whh0f = (const float*)d_in[3];
    const float* bih0f = (const float*)d_in[4];
    const float* bhh0f = (const float*)d_in[5];
    const float* wih0b = (const float*)d_in[6];
    const float* whh0b = (const float*)d_in[7];
    const float* bih0b = (const float*)d_in[8];
    const float* bhh0b = (const float*)d_in[9];
    const float* wih1f = (const float*)d_in[10];
    const float* whh1f = (const float*)d_in[11];
    const float* bih1f = (const float*)d_in[12];
    const float* bhh1f = (const float*)d_in[13];
    const float* wih1b = (const float*)d_in[14];
    const float* whh1b = (const float*)d_in[15];
    const float* bih1b = (const float*)d_in[16];
    const float* bhh1b = (const float*)d_in[17];

    if (ws_size < (size_t)WS_NEED) {
        sentinel<<<1, 1, 0, stream>>>((float*)d_out);
        return;
    }
    char* ws = (char*)d_ws;
    bf16* gi    = (bf16*)(ws + GI_OFF);
    bf16* l0out = (bf16*)(ws + L0_OFF);
    bf16* xb    = (bf16*)(ws + XB_OFF);
    bf16* w0    = (bf16*)(ws + W0_OFF);
    bf16* w1    = (bf16*)(ws + W1_OFF);
    u32*  hbuf  = (u32*)(ws + HB_OFF);
    float* hn   = (float*)d_out + (long)TB * 1024;

    // 0xFF = tag-bit-1 everywhere: cold/stale buffers mismatch the first
    // expected generations (d=0,1 have tag 0), so polls wait for real data.
    // Between layers no re-memset is needed: layer 0 ends with gens 510/511
    // (both tag 1) resident, and layer 1 starts expecting tag 0.
    hipMemsetAsync(hbuf, 0xFF, HB_BYTES, stream);

    // bf16 packing
    cvt_f32_bf16<<<2048, 256, 0, stream>>>(x, xb, (long)TB * 512);
    cvt_f32_bf16<<<256, 256, 0, stream>>>(wih0f, w0,             (long)G3 * 512);
    cvt_f32_bf16<<<256, 256, 0, stream>>>(wih0b, w0 + G3*512L,   (long)G3 * 512);
    cvt_f32_bf16<<<256, 256, 0, stream>>>(wih1f, w1,             (long)G3 * 1024);
    cvt_f32_bf16<<<256, 256, 0, stream>>>(wih1b, w1 + G3*1024L,  (long)G3 * 1024);

    // layer 0
    gemm_gi<<<dim3(256 * 24), 256, 0, stream>>>(xb, w0, gi, 512);
    gru_rec<<<32, 256, 0, stream>>>(gi, whh0f, whh0b, bih0f, bhh0f, bih0b, bhh0b,
                                    h0, hbuf, (void*)l0out, hn, 0, 0);
    // layer 1
    gemm_gi<<<dim3(256 * 24), 256, 0, stream>>>(l0out, w1, gi, 1024);
    gru_rec<<<32, 256, 0, stream>>>(gi, whh1f, whh1b, bih1f, bhh1f, bih1b, bhh1b,
                                    h0, hbuf, d_out, hn, 1, 1);
}

// Round 4
// 5111.472 us; speedup vs baseline: 1.3040x; 1.3040x over previous
//
#include <hip/hip_runtime.h>
#include <hip/hip_bf16.h>

typedef __bf16 bf16;
typedef bf16 bf16x8 __attribute__((ext_vector_type(8)));
typedef float f32x4 __attribute__((ext_vector_type(4)));
typedef unsigned int u32;
typedef u32 u32x4 __attribute__((ext_vector_type(4)));

#define AGENT __HIP_MEMORY_SCOPE_AGENT

// ---- problem sizes ----
#define TT 512
#define BB 64
#define HH 512
#define TB (TT*BB)      // 32768 rows
#define G3 (3*HH)       // 1536 gates per dir

// ---- workspace layout (bytes) ----
#define GI_OFF   0L
#define GI_BYTES (2L*TB*G3*2)          // bf16 gi, both dirs
#define L0_OFF   (GI_OFF + GI_BYTES)
#define L0_BYTES (1L*TB*1024*2)        // bf16 layer-0 output
#define XB_OFF   (L0_OFF + L0_BYTES)
#define XB_BYTES (1L*TB*512*2)         // bf16 x
#define W0_OFF   (XB_OFF + XB_BYTES)
#define W0_BYTES (3072L*512*2)         // packed w_ih L0 (f then b)
#define W1_OFF   (W0_OFF + W0_BYTES)
#define W1_BYTES (3072L*1024*2)        // packed w_ih L1
#define HB_OFF   (W1_OFF + W1_BYTES)
#define HB_BYTES (2L*2*64*256*4)       // h exchange: [phase][dir][64][256] u32 (bf16 pairs)
#define FL_OFF   (HB_OFF + HB_BYTES)
#define FL_BYTES 1024                  // (unused; kept for ws sizing stability)
#define WS_NEED  (FL_OFF + FL_BYTES)

// ============================ helpers ============================
__device__ __forceinline__ float sigm(float x) {
    return __builtin_amdgcn_rcpf(1.0f + __expf(-x));
}
__device__ __forceinline__ float tanh_f(float x) {
    return 1.0f - 2.0f * __builtin_amdgcn_rcpf(1.0f + __expf(2.0f * x));
}

// ============================ kernels ============================
__global__ void sentinel(float* o) { o[0] = 1.0e9f; }  // ws too small marker

__global__ void cvt_f32_bf16(const float* __restrict__ s, bf16* __restrict__ d, long n) {
    long i = (long)blockIdx.x * blockDim.x + threadIdx.x;
    long st = (long)gridDim.x * blockDim.x;
    for (; i < n; i += st) d[i] = (bf16)s[i];
}

// C[m, n] = sum_k A[m,k] * Bw[n,k]; A row-major [32768,K] bf16, Bw [3072,K] bf16.
// Output written as bf16 into gi[dir][m][col], dir = n>=1536.
__global__ __launch_bounds__(256, 2)
void gemm_gi(const bf16* __restrict__ A, const bf16* __restrict__ Bw,
             bf16* __restrict__ gi, int K)
{
    __shared__ bf16 aS[128*72];
    __shared__ bf16 bS[128*72];
    const int tid = threadIdx.x;
    const int mt = blockIdx.x & 255;
    const int nt = blockIdx.x >> 8;
    const long m0 = (long)mt * 128;
    const int n0 = nt * 128;
    const int wave = tid >> 6, lane = tid & 63;
    const int q = lane >> 4, lr = lane & 15;
    const int wm = wave & 1, wn = wave >> 1;
    f32x4 acc[4][4] = {};

    for (int kb = 0; kb < K; kb += 64) {
        __syncthreads();
        #pragma unroll
        for (int p = 0; p < 4; ++p) {
            int idx = tid + p * 256;
            int row = idx >> 3, qd = idx & 7;
            *(uint4*)(aS + row*72 + qd*8) = *(const uint4*)(A + (m0+row)*K + kb + qd*8);
            *(uint4*)(bS + row*72 + qd*8) = *(const uint4*)(Bw + (long)(n0+row)*K + kb + qd*8);
        }
        __syncthreads();
        #pragma unroll
        for (int kk = 0; kk < 2; ++kk) {
            bf16x8 af[4], bfr[4];
            #pragma unroll
            for (int sm = 0; sm < 4; ++sm)
                af[sm] = *(const bf16x8*)(aS + (wm*64 + sm*16 + lr)*72 + kk*32 + q*8);
            #pragma unroll
            for (int sn = 0; sn < 4; ++sn)
                bfr[sn] = *(const bf16x8*)(bS + (wn*64 + sn*16 + lr)*72 + kk*32 + q*8);
            #pragma unroll
            for (int sm = 0; sm < 4; ++sm)
                #pragma unroll
                for (int sn = 0; sn < 4; ++sn)
                    acc[sm][sn] = __builtin_amdgcn_mfma_f32_16x16x32_bf16(
                        af[sm], bfr[sn], acc[sm][sn], 0, 0, 0);
        }
    }
    #pragma unroll
    for (int sm = 0; sm < 4; ++sm) {
        #pragma unroll
        for (int sn = 0; sn < 4; ++sn) {
            int n_g = n0 + wn*64 + sn*16 + lr;
            int d = (n_g >= G3) ? 1 : 0;
            int cg = n_g - d * G3;
            u32* gout = (u32*)(gi + (long)d * TB * G3);
            #pragma unroll
            for (int i = 0; i < 4; ++i) {
                long m_g = m0 + wm*64 + sm*16 + q*4 + i;
                unsigned short hs = __builtin_bit_cast(unsigned short, (bf16)acc[sm][sn][i]);
                int other = __shfl_xor((int)hs, 1, 64);
                if (!(lr & 1))
                    gout[(m_g * G3 + cg) >> 1] = (u32)hs | (((u32)(unsigned short)other) << 16);
            }
        }
    }
}

// Persistent recurrence: 64 blocks (2 dirs x 32 h-slices of 16 cols), 256 thr.
//
// Round-4 change: W ENTIRELY IN REGISTERS. The 48 B-fragments each wave read
// from LDS every step are the same for all 512 steps (W is stationary).
// Round-3's regression proved LDS streaming sits on the serial per-step path
// (~12 cy/b128 x 192 reads/block/step ~ 0.96us). Hoisting to 48x bf16x8
// (192 VGPRs) makes the K-loop register-only: poll -> strip -> 48 MFMAs ->
// gates -> publish, with no lgkmcnt on the path. ~300 VGPRs total still
// gives the same 1 block/CU occupancy (launch_bounds(256,1)).
//
// Sync protocol (unchanged from round 2): SELF-VALIDATING DATA.
// GRU guarantees |h| < 1 < 2, so bit14 of every published bf16 (exponent
// MSB) is always 0. tag(d) = (d>>1)&1 for generation d in phase buffer d&1.
// Producer ORs the tag into each packed u32 and stores fire-and-forget
// (relaxed agent scope). Consumer polls by loading the h tile itself with
// sc0 sc1 and validating every u32's tag; torn old/new mixes are caught
// per-u32. Tag bits are STRIPPED (AND 0xBFFFBFFF) before the MFMAs (bit14
// = x2^128) -- only needed on tag-1 steps (wave-uniform skip otherwise).
// Deadlock-free by induction from the pre-loop publish(0); ABA-free because
// gen d+2 cannot exist before all blocks consumed gen d+1.
__global__ __launch_bounds__(256, 1)
void gru_rec(const bf16* __restrict__ gi,
             const float* __restrict__ whh_f, const float* __restrict__ whh_b,
             const float* __restrict__ bih_f, const float* __restrict__ bhh_f,
             const float* __restrict__ bih_b, const float* __restrict__ bhh_b,
             const float* __restrict__ h0,
             u32* hbuf,
             void* out, float* hn_out, int layer, int out_f32)
{
    __shared__ bf16 wS[48*512];   // XOR-swizzled: chunk c stored at c^(row&7)
    const int tid = threadIdx.x;
    const int dir = blockIdx.x & 1;
    const int slice = blockIdx.x >> 1;       // 0..31
    const int wave = tid >> 6, lane = tid & 63;
    const int q = lane >> 4, lr = lane & 15;

    const float* whh = dir ? whh_b : whh_f;
    const float* bih = dir ? bih_b : bih_f;
    const float* bhh = dir ? bhh_b : bhh_f;

    // stage W_hh slice -> LDS bf16, 16B chunks, XOR bank swizzle
    for (int idx = tid; idx < 48*64; idx += 256) {
        int row = idx >> 6, c = idx & 63;
        int g = row >> 4, cc = row & 15;
        const float* src = whh + (size_t)(g*HH + slice*16 + cc)*HH + c*8;
        bf16x8 v;
        #pragma unroll
        for (int j = 0; j < 8; ++j) v[j] = (bf16)src[j];
        *(bf16x8*)(wS + row*512 + ((c ^ (row & 7)) << 3)) = v;
    }
    __syncthreads();

    const int sw = lr & 7;

    // ---- hoist W fragments LDS -> registers, ONCE (48 x bf16x8 = 192 VGPR).
    // wf[g][KK] is the B-operand for gate g, k-slice KK, all 512 steps.
    bf16x8 wf[3][16];
    #pragma unroll
    for (int g = 0; g < 3; ++g)
        #pragma unroll
        for (int KK = 0; KK < 16; ++KK)
            wf[g][KK] = *(const bf16x8*)(wS + (g*16 + lr)*512 + (((KK*4 + q) ^ sw) << 3));

    const int col = slice*16 + lr;
    const float bi0 = bih[col], bi1 = bih[HH+col], bi2 = bih[2*HH+col];
    const float bh0 = bhh[col], bh1 = bhh[HH+col], bh2 = bhh[2*HH+col];
    const int mrow = wave*16 + q*4;

    float hprev[4];
    #pragma unroll
    for (int i = 0; i < 4; ++i)
        hprev[i] = h0[((2*layer + dir)*BB + mrow + i)*HH + col];

    // publish hv[] into phase buffer ph with tag pattern pat (fire-and-forget)
    auto publish = [&](int ph, u32 pat, const float* hv) {
        u32* hb = hbuf + (((ph << 1) | dir) * 64) * 256;
        #pragma unroll
        for (int i = 0; i < 4; ++i) {
            unsigned short hs = __builtin_bit_cast(unsigned short, (bf16)hv[i]);
            int other = __shfl_xor((int)hs, 1, 64);
            if (!(lr & 1)) {
                u32 u = ((u32)hs | (((u32)(unsigned short)other) << 16)) | pat;
                __hip_atomic_store(hb + (mrow + i)*256 + (col >> 1), u,
                                   __ATOMIC_RELAXED, AGENT);
            }
        }
    };

    // initial h publish: generation d=0, phase 0, tag 0 (needs |h0|<2; h0=0 here)
    publish(0, 0u, hprev);

    const bf16* gbase = gi + (long)dir * TB * G3;
    bf16 gp[3][4];
    {
        int t0 = dir ? (TT-1) : 0;
        #pragma unroll
        for (int g = 0; g < 3; ++g)
            #pragma unroll
            for (int i = 0; i < 4; ++i)
                gp[g][i] = gbase[(long)(t0*BB + mrow + i)*G3 + g*HH + col];
    }

    for (int s = 0; s < TT; ++s) {
        const int t = dir ? (TT-1-s) : s;
        const u32 pat = (s & 2) ? 0x40004000u : 0u;   // tag(d=s) = (s>>1)&1
        const u32* hr = hbuf + ((((s & 1) << 1) | dir)*64 + wave*16 + lr)*256 + q*4;
        u32x4 a0,a1,a2,a3,a4,a5,a6,a7,a8,a9,a10,a11,a12,a13,a14,a15;
        // ---- poll-the-data: load 16x dwordx4 (L1/L2-bypassing), validate tags
        for (;;) {
            asm volatile(
                "global_load_dwordx4 %0, %16, off sc0 sc1\n\t"
                "global_load_dwordx4 %1, %16, off offset:64 sc0 sc1\n\t"
                "global_load_dwordx4 %2, %16, off offset:128 sc0 sc1\n\t"
                "global_load_dwordx4 %3, %16, off offset:192 sc0 sc1\n\t"
                "global_load_dwordx4 %4, %16, off offset:256 sc0 sc1\n\t"
                "global_load_dwordx4 %5, %16, off offset:320 sc0 sc1\n\t"
                "global_load_dwordx4 %6, %16, off offset:384 sc0 sc1\n\t"
                "global_load_dwordx4 %7, %16, off offset:448 sc0 sc1\n\t"
                "global_load_dwordx4 %8, %16, off offset:512 sc0 sc1\n\t"
                "global_load_dwordx4 %9, %16, off offset:576 sc0 sc1\n\t"
                "global_load_dwordx4 %10, %16, off offset:640 sc0 sc1\n\t"
                "global_load_dwordx4 %11, %16, off offset:704 sc0 sc1\n\t"
                "global_load_dwordx4 %12, %16, off offset:768 sc0 sc1\n\t"
                "global_load_dwordx4 %13, %16, off offset:832 sc0 sc1\n\t"
                "global_load_dwordx4 %14, %16, off offset:896 sc0 sc1\n\t"
                "global_load_dwordx4 %15, %16, off offset:960 sc0 sc1\n\t"
                "s_waitcnt vmcnt(0)"
                : "=&v"(a0),"=&v"(a1),"=&v"(a2),"=&v"(a3),
                  "=&v"(a4),"=&v"(a5),"=&v"(a6),"=&v"(a7),
                  "=&v"(a8),"=&v"(a9),"=&v"(a10),"=&v"(a11),
                  "=&v"(a12),"=&v"(a13),"=&v"(a14),"=&v"(a15)
                : "v"(hr)
                : "memory");
#define ORV(v)  (v[0] | v[1] | v[2] | v[3])
#define ANDV(v) (v[0] & v[1] & v[2] & v[3])
            bool ok;
            if (pat) {
                u32 g = ANDV(a0) & ANDV(a1) & ANDV(a2)  & ANDV(a3)
                      & ANDV(a4) & ANDV(a5) & ANDV(a6)  & ANDV(a7)
                      & ANDV(a8) & ANDV(a9) & ANDV(a10) & ANDV(a11)
                      & ANDV(a12)& ANDV(a13)& ANDV(a14) & ANDV(a15);
                ok = (g & 0x40004000u) == 0x40004000u;
            } else {
                u32 b = ORV(a0) | ORV(a1) | ORV(a2)  | ORV(a3)
                      | ORV(a4) | ORV(a5) | ORV(a6)  | ORV(a7)
                      | ORV(a8) | ORV(a9) | ORV(a10) | ORV(a11)
                      | ORV(a12)| ORV(a13)| ORV(a14) | ORV(a15);
                ok = (b & 0x40004000u) == 0u;
            }
#undef ORV
#undef ANDV
            if (__all((int)ok)) break;
        }
        // ---- strip tag bits (bit14 == x2^128 -- must NOT reach the MFMAs).
        // Only on tag-1 steps (wave-uniform branch; tag-0 data is already clean).
        if (pat) {
            const u32 SM = 0xBFFFBFFFu;
            auto strip = [&](u32x4& v) {
                v[0] &= SM; v[1] &= SM; v[2] &= SM; v[3] &= SM;
            };
            strip(a0);  strip(a1);  strip(a2);  strip(a3);
            strip(a4);  strip(a5);  strip(a6);  strip(a7);
            strip(a8);  strip(a9);  strip(a10); strip(a11);
            strip(a12); strip(a13); strip(a14); strip(a15);
        }
        // ---- 48 MFMAs, register-only (gh = h @ W_slice^T)
        f32x4 acc0 = {0,0,0,0}, acc1 = {0,0,0,0}, acc2 = {0,0,0,0};
#define KSTEP(KK, AU) { \
            bf16x8 av = __builtin_bit_cast(bf16x8, AU); \
            acc0 = __builtin_amdgcn_mfma_f32_16x16x32_bf16(av, wf[0][KK], acc0, 0,0,0); \
            acc1 = __builtin_amdgcn_mfma_f32_16x16x32_bf16(av, wf[1][KK], acc1, 0,0,0); \
            acc2 = __builtin_amdgcn_mfma_f32_16x16x32_bf16(av, wf[2][KK], acc2, 0,0,0); }
        KSTEP(0,a0)  KSTEP(1,a1)  KSTEP(2,a2)  KSTEP(3,a3)
        KSTEP(4,a4)  KSTEP(5,a5)  KSTEP(6,a6)  KSTEP(7,a7)
        KSTEP(8,a8)  KSTEP(9,a9)  KSTEP(10,a10) KSTEP(11,a11)
        KSTEP(12,a12) KSTEP(13,a13) KSTEP(14,a14) KSTEP(15,a15)
#undef KSTEP
        // ---- fused gates (fp32)
        float hnew[4];
        #pragma unroll
        for (int i = 0; i < 4; ++i) {
            float r = sigm((float)gp[0][i] + bi0 + acc0[i] + bh0);
            float z = sigm((float)gp[1][i] + bi1 + acc1[i] + bh1);
            float n = tanh_f((float)gp[2][i] + bi2 + r * (acc2[i] + bh2));
            float h = (1.0f - z) * n + z * hprev[i];
            hprev[i] = h;
            hnew[i] = h;
        }
        // ---- publish h_new immediately (self-validating: no ack, no flag)
        if (s < TT-1) {
            u32 npat = ((s+1) & 2) ? 0x40004000u : 0u;  // tag(d=s+1)
            publish((s+1) & 1, npat, hnew);
        }
        // ---- write y[t]
        if (out_f32) {
            float* yo = (float*)out;
            #pragma unroll
            for (int i = 0; i < 4; ++i)
                yo[(long)(t*BB + mrow + i)*1024 + dir*HH + col] = hnew[i];
        } else {
            bf16* yo = (bf16*)out;
            #pragma unroll
            for (int i = 0; i < 4; ++i)
                yo[(long)(t*BB + mrow + i)*1024 + dir*HH + col] = (bf16)hnew[i];
        }
        if (s == TT-1) {
            #pragma unroll
            for (int i = 0; i < 4; ++i)
                hn_out[((2*layer + dir)*BB + mrow + i)*HH + col] = hnew[i];
            break;
        }
        // ---- prefetch next gi (hides under the next poll)
        int tn = dir ? (TT-2-s) : (s+1);
        #pragma unroll
        for (int g = 0; g < 3; ++g)
            #pragma unroll
            for (int i = 0; i < 4; ++i)
                gp[g][i] = gbase[(long)(tn*BB + mrow + i)*G3 + g*HH + col];
    }
}

// ============================ launch ============================
extern "C" void kernel_launch(void* const* d_in, const int* in_sizes, int n_in,
                              void* d_out, int out_size, void* d_ws, size_t ws_size,
                              hipStream_t stream)
{
    const float* x     = (const float*)d_in[0];
    const float* h0    = (const float*)d_in[1];
    const float* wih0f = (const float*)d_in[2];
    const float* whh0f = (const float*)d_in[3];
    const float* bih0f = (const float*)d_in[4];
    const float* bhh0f = (const float*)d_in[5];
    const float* wih0b = (const float*)d_in[6];
    const float* whh0b = (const float*)d_in[7];
    const float* bih0b = (const float*)d_in[8];
    const float* bhh0b = (const float*)d_in[9];
    const float* wih1f = (const float*)d_in[10];
    const float* whh1f = (const float*)d_in[11];
    const float* bih1f = (const float*)d_in[12];
    const float* bhh1f = (const float*)d_in[13];
    const float* wih1b = (const float*)d_in[14];
    const float* whh1b = (const float*)d_in[15];
    const float* bih1b = (const float*)d_in[16];
    const float* bhh1b = (const float*)d_in[17];

    if (ws_size < (size_t)WS_NEED) {
        sentinel<<<1, 1, 0, stream>>>((float*)d_out);
        return;
    }
    char* ws = (char*)d_ws;
    bf16* gi    = (bf16*)(ws + GI_OFF);
    bf16* l0out = (bf16*)(ws + L0_OFF);
    bf16* xb    = (bf16*)(ws + XB_OFF);
    bf16* w0    = (bf16*)(ws + W0_OFF);
    bf16* w1    = (bf16*)(ws + W1_OFF);
    u32*  hbuf  = (u32*)(ws + HB_OFF);
    float* hn   = (float*)d_out + (long)TB * 1024;

    // 0xFF = tag-bit-1 everywhere: cold/stale buffers mismatch the first
    // expected generations (d=0,1 have tag 0), so polls wait for real data.
    // Between layers no re-memset is needed: layer 0 ends with gens 510/511
    // (both tag 1) resident, and layer 1 starts expecting tag 0.
    hipMemsetAsync(hbuf, 0xFF, HB_BYTES, stream);

    // bf16 packing
    cvt_f32_bf16<<<2048, 256, 0, stream>>>(x, xb, (long)TB * 512);
    cvt_f32_bf16<<<256, 256, 0, stream>>>(wih0f, w0,             (long)G3 * 512);
    cvt_f32_bf16<<<256, 256, 0, stream>>>(wih0b, w0 + G3*512L,   (long)G3 * 512);
    cvt_f32_bf16<<<256, 256, 0, stream>>>(wih1f, w1,             (long)G3 * 1024);
    cvt_f32_bf16<<<256, 256, 0, stream>>>(wih1b, w1 + G3*1024L,  (long)G3 * 1024);

    // layer 0
    gemm_gi<<<dim3(256 * 24), 256, 0, stream>>>(xb, w0, gi, 512);
    gru_rec<<<64, 256, 0, stream>>>(gi, whh0f, whh0b, bih0f, bhh0f, bih0b, bhh0b,
                                    h0, hbuf, (void*)l0out, hn, 0, 0);
    // layer 1
    gemm_gi<<<dim3(256 * 24), 256, 0, stream>>>(l0out, w1, gi, 1024);
    gru_rec<<<64, 256, 0, stream>>>(gi, whh1f, whh1b, bih1f, bhh1f, bih1b, bhh1b,
                                    h0, hbuf, d_out, hn, 1, 1);
}